// Round 1
// baseline (151.554 us; speedup 1.0000x reference)
//
#include <hip/hip_runtime.h>
#include <math.h>

#define NSTEP_ 128
#define NSYS_  256

// One thread per system. Block-tridiagonal KKT solve (block-Thomas with 3x3
// Cholesky pivots) in f64. Constraints x0=iv0, x1=iv1 are eliminated by
// zeroing rows/cols 0,1 of G with unit diagonal + RHS adjustment (exactly
// equivalent to the reference's KKT solve).
__global__ __launch_bounds__(64)
void ode_kkt_solve(const float* __restrict__ coeffs,
                   const float* __restrict__ rhs,
                   const float* __restrict__ ivr,
                   const float* __restrict__ steps,
                   float* __restrict__ out)
{
    const int sys = blockIdx.x * blockDim.x + threadIdx.x;
    if (sys >= NSYS_) return;

    const float* cP  = coeffs + (size_t)sys * NSTEP_ * 3;
    const float* rP  = rhs    + (size_t)sys * NSTEP_;
    const float* ivP = ivr    + (size_t)sys * 2;
    const float* hP  = steps  + (size_t)sys * (NSTEP_ - 1);

    double W[NSTEP_-1][3][3];   // W_t = S_t^{-1} E_t   (scratch)
    double zarr[NSTEP_][3];     // z_t = S_t^{-1} r'_t  (scratch)

    double Sacc[3][3] = {{0,0,0},{0,0,0},{0,0,0}}; // carry into D_{t}: window bottom-right - E^T W
    double radj[3]  = {0,0,0};                     // carry into r_t: -E^T z (+ iv coupling at t==1)
    double extra[3] = {0,0,0};

    const double iv0 = (double)ivP[0];
    const double iv1 = (double)ivP[1];

    for (int t = 0; t < NSTEP_; ++t) {
        double D[3][3], E[3][3], rt[3], carry[3][3];
        const double cv[3] = { (double)cP[t*3+0], (double)cP[t*3+1], (double)cP[t*3+2] };
        const double rv = (double)rP[t];
        #pragma unroll
        for (int a = 0; a < 3; ++a) {
            #pragma unroll
            for (int b = 0; b < 3; ++b) {
                D[a][b] = Sacc[a][b] + cv[a]*cv[b];   // equation row contribution
                E[a][b] = 0.0;
                carry[a][b] = 0.0;
            }
            rt[a] = cv[a]*rv + radj[a];
        }
        const bool hasE = (t < NSTEP_-1);
        if (hasE) {
            const double h  = (double)hP[t];
            const double ih = 1.0 / h;
            const double s1 = ih * ih;     // h^-2  (i=1 smoothness scale)
            const double s0 = s1 * ih;     // h^-3  (i=0 smoothness scale)
            // 5 interface rows as 6-vectors over [block t | block t+1]
            const double w[5][6] = {
                {  s0,   s0*h, 0.5*s0*h*h, -s0,   0.0,   0.0        }, // Af, i=0
                { -s0,   0.0,  0.0,         s0,  -s0*h,  0.5*s0*h*h }, // Ab, i=0
                {  0.0,  s1,   s1*h,        0.0, -s1,    0.0        }, // Af, i=1
                {  0.0, -s1,   0.0,         0.0,  s1,   -s1*h       }, // Ab, i=1
                {  0.0,  0.0, -ih,          0.0,  0.0,   ih         }  // top-order diff
            };
            #pragma unroll
            for (int k = 0; k < 5; ++k)
                #pragma unroll
                for (int a = 0; a < 3; ++a)
                    #pragma unroll
                    for (int b = 0; b < 3; ++b) {
                        D[a][b]     += w[k][a]   * w[k][b];
                        E[a][b]     += w[k][a]   * w[k][b+3];
                        carry[a][b] += w[k][a+3] * w[k][b+3];
                    }
        }
        if (t == 0) {
            // RHS adjustment for fixed vars, block 0 (G(0,0) = D_0)
            #pragma unroll
            for (int a = 0; a < 3; ++a) rt[a] -= D[a][0]*iv0 + D[a][1]*iv1;
            rt[0] = iv0; rt[1] = iv1;
            // zero rows/cols 0,1 of D, unit diag
            #pragma unroll
            for (int a = 0; a < 3; ++a) { D[0][a]=0.0; D[1][a]=0.0; D[a][0]=0.0; D[a][1]=0.0; }
            D[0][0] = 1.0; D[1][1] = 1.0;
            // block-1 RHS coupling: G(1,0) = E_0^T -> r_1 -= E0[0][:]*iv0 + E0[1][:]*iv1
            #pragma unroll
            for (int b = 0; b < 3; ++b) extra[b] = -(E[0][b]*iv0 + E[1][b]*iv1);
            // zero rows 0,1 of E_0
            #pragma unroll
            for (int b = 0; b < 3; ++b) { E[0][b] = 0.0; E[1][b] = 0.0; }
        }

        // Cholesky of S_t (= D after accumulations)
        const double l00 = sqrt(D[0][0]);
        const double i00 = 1.0 / l00;
        const double l10 = D[1][0] * i00;
        const double l20 = D[2][0] * i00;
        const double l11 = sqrt(D[1][1] - l10*l10);
        const double i11 = 1.0 / l11;
        const double l21 = (D[2][1] - l20*l10) * i11;
        const double l22 = sqrt(D[2][2] - l20*l20 - l21*l21);
        const double i22 = 1.0 / l22;

        // z_t = S^{-1} r'
        {
            const double y0 = rt[0] * i00;
            const double y1 = (rt[1] - l10*y0) * i11;
            const double y2 = (rt[2] - l20*y0 - l21*y1) * i22;
            const double x2 = y2 * i22;
            const double x1 = (y1 - l21*x2) * i11;
            const double x0 = (y0 - l10*x1 - l20*x2) * i00;
            zarr[t][0] = x0; zarr[t][1] = x1; zarr[t][2] = x2;
        }
        if (hasE) {
            // W_t = S^{-1} E_t (column-wise)
            #pragma unroll
            for (int b = 0; b < 3; ++b) {
                const double y0 = E[0][b] * i00;
                const double y1 = (E[1][b] - l10*y0) * i11;
                const double y2 = (E[2][b] - l20*y0 - l21*y1) * i22;
                const double x2 = y2 * i22;
                const double x1 = (y1 - l21*x2) * i11;
                const double x0 = (y0 - l10*x1 - l20*x2) * i00;
                W[t][0][b] = x0; W[t][1][b] = x1; W[t][2][b] = x2;
            }
            // S_{t+1} = D_{t+1} - E^T W ; r'_{t+1} = r_{t+1} - E^T z (+ iv coupling)
            #pragma unroll
            for (int a = 0; a < 3; ++a)
                #pragma unroll
                for (int b = 0; b < 3; ++b)
                    Sacc[a][b] = carry[a][b]
                        - (E[0][a]*W[t][0][b] + E[1][a]*W[t][1][b] + E[2][a]*W[t][2][b]);
            #pragma unroll
            for (int b = 0; b < 3; ++b) {
                radj[b] = extra[b]
                        - (E[0][b]*zarr[t][0] + E[1][b]*zarr[t][1] + E[2][b]*zarr[t][2]);
                extra[b] = 0.0;
            }
        }
    }

    // back substitution + outputs (f32)
    float* u0 = out;
    float* u1 = out + 32768;
    float* u2 = out + 65536;
    double x[3] = { zarr[NSTEP_-1][0], zarr[NSTEP_-1][1], zarr[NSTEP_-1][2] };
    u0[sys*NSTEP_ + (NSTEP_-1)] = (float)x[0];
    u1[sys*NSTEP_ + (NSTEP_-1)] = (float)x[1];
    u2[sys*NSTEP_ + (NSTEP_-1)] = (float)x[2];
    for (int t = NSTEP_-2; t >= 0; --t) {
        double xn[3];
        #pragma unroll
        for (int a = 0; a < 3; ++a)
            xn[a] = zarr[t][a] - (W[t][a][0]*x[0] + W[t][a][1]*x[1] + W[t][a][2]*x[2]);
        x[0] = xn[0]; x[1] = xn[1]; x[2] = xn[2];
        u0[sys*NSTEP_ + t] = (float)x[0];
        u1[sys*NSTEP_ + t] = (float)x[1];
        u2[sys*NSTEP_ + t] = (float)x[2];
    }

    // output 3: scalar zero; output 4: steps pass-through
    float* outH = out + 98305;
    for (int j = 0; j < NSTEP_-1; ++j) outH[sys*(NSTEP_-1) + j] = hP[j];
    if (sys == 0) out[98304] = 0.0f;
}

extern "C" void kernel_launch(void* const* d_in, const int* in_sizes, int n_in,
                              void* d_out, int out_size, void* d_ws, size_t ws_size,
                              hipStream_t stream) {
    const float* coeffs = (const float*)d_in[0];
    const float* rhs    = (const float*)d_in[1];
    const float* ivr    = (const float*)d_in[2];
    const float* steps  = (const float*)d_in[3];
    float* out = (float*)d_out;
    (void)in_sizes; (void)n_in; (void)out_size; (void)d_ws; (void)ws_size;
    hipLaunchKernelGGL(ode_kkt_solve, dim3(4), dim3(64), 0, stream,
                       coeffs, rhs, ivr, steps, out);
}

// Round 2
// 12.626 us; speedup vs baseline: 12.0029x; 12.0029x over previous
//
#include <hip/hip_runtime.h>
#include <math.h>

#define NSTEP_ 128
#define NSYS_  256
#define STRIDE 21   // per-row LDS doubles: Dinv[9] | U[9] | r[3]

// Symmetric 3x3 inverse via adjugate; reads lower triangle of D only.
__device__ __forceinline__ void sym_inv3(const double D[9], double Dinv[9]) {
    const double a = D[0], b = D[3], c = D[4], d = D[6], e = D[7], f = D[8];
    const double A00 = c*f - e*e;
    const double A01 = d*e - b*f;
    const double A02 = b*e - c*d;
    const double A11 = a*f - d*d;
    const double A12 = b*d - a*e;
    const double A22 = a*c - b*b;
    const double det  = a*A00 + b*A01 + d*A02;
    const double idet = 1.0 / det;
    Dinv[0] = A00*idet; Dinv[1] = A01*idet; Dinv[2] = A02*idet;
    Dinv[3] = A01*idet; Dinv[4] = A11*idet; Dinv[5] = A12*idet;
    Dinv[6] = A02*idet; Dinv[7] = A12*idet; Dinv[8] = A22*idet;
}

// Interface rows for step size h: 5 rows, left half (block t) and right half
// (block t+1). Matches the reference _build_A exactly (verified round 1).
__device__ __forceinline__ void iface_rows(double h, double wL[5][3], double wR[5][3]) {
    const double ih = 1.0 / h;
    const double s1 = ih * ih;        // h^-2
    const double s0 = s1 * ih;        // h^-3
    const double hh = 0.5 * ih;       // 0.5 * s0 * h^2
    // k0: Af,i=0   k1: Ab,i=0   k2: Af,i=1   k3: Ab,i=1   k4: top-order diff
    wL[0][0] =  s0; wL[0][1] =  s1; wL[0][2] =  hh;
    wR[0][0] = -s0; wR[0][1] = 0.0; wR[0][2] = 0.0;
    wL[1][0] = -s0; wL[1][1] = 0.0; wL[1][2] = 0.0;
    wR[1][0] =  s0; wR[1][1] = -s1; wR[1][2] =  hh;
    wL[2][0] = 0.0; wL[2][1] =  s1; wL[2][2] =  ih;
    wR[2][0] = 0.0; wR[2][1] = -s1; wR[2][2] = 0.0;
    wL[3][0] = 0.0; wL[3][1] = -s1; wL[3][2] = 0.0;
    wR[3][0] = 0.0; wR[3][1] =  s1; wR[3][2] = -ih;
    wL[4][0] = 0.0; wL[4][1] = 0.0; wL[4][2] = -ih;
    wR[4][0] = 0.0; wR[4][1] = 0.0; wR[4][2] =  ih;
}

// One system per block (128 threads = 1 block-row per thread).
// Block-tridiagonal SPD solve by parallel cyclic reduction, f64.
__global__ __launch_bounds__(128)
void ode_pcr_solve(const float* __restrict__ coeffs,
                   const float* __restrict__ rhs,
                   const float* __restrict__ ivr,
                   const float* __restrict__ steps,
                   float* __restrict__ out)
{
    const int sys = blockIdx.x;
    const int t   = threadIdx.x;

    const float* cP  = coeffs + (size_t)sys * NSTEP_ * 3;
    const float* rP  = rhs    + (size_t)sys * NSTEP_;
    const float* ivP = ivr    + (size_t)sys * 2;
    const float* hP  = steps  + (size_t)sys * (NSTEP_ - 1);

    __shared__ double sh[NSTEP_ * STRIDE];

    // ---------------- assembly of row t: D (3x3 sym), U (3x3), r (3) --------
    double D[9], U[9], r[3];
    {
        const double cv0 = (double)cP[t*3+0];
        const double cv1 = (double)cP[t*3+1];
        const double cv2 = (double)cP[t*3+2];
        const double rv  = (double)rP[t];
        const double cv[3] = {cv0, cv1, cv2};
        #pragma unroll
        for (int a = 0; a < 3; ++a) {
            #pragma unroll
            for (int b = 0; b < 3; ++b) { D[a*3+b] = cv[a]*cv[b]; U[a*3+b] = 0.0; }
            r[a] = cv[a]*rv;
        }
        if (t < NSTEP_-1) {              // interface t (this row is left block)
            double wL[5][3], wR[5][3];
            iface_rows((double)hP[t], wL, wR);
            #pragma unroll
            for (int k = 0; k < 5; ++k)
                #pragma unroll
                for (int a = 0; a < 3; ++a)
                    #pragma unroll
                    for (int b = 0; b < 3; ++b) {
                        D[a*3+b] += wL[k][a]*wL[k][b];
                        U[a*3+b] += wL[k][a]*wR[k][b];
                    }
        }
        if (t >= 1) {                    // interface t-1 (this row is right block)
            double wL[5][3], wR[5][3];
            iface_rows((double)hP[t-1], wL, wR);
            #pragma unroll
            for (int k = 0; k < 5; ++k)
                #pragma unroll
                for (int a = 0; a < 3; ++a)
                    #pragma unroll
                    for (int b = 0; b < 3; ++b)
                        D[a*3+b] += wR[k][a]*wR[k][b];
            if (t == 1) {
                // RHS coupling from fixed vars via ORIGINAL U0 rows 0,1:
                // r_1 -= U0[0][:]*iv0 + U0[1][:]*iv1
                const double iv0 = (double)ivP[0];
                const double iv1 = (double)ivP[1];
                #pragma unroll
                for (int b = 0; b < 3; ++b) {
                    double u0b = 0.0, u1b = 0.0;
                    #pragma unroll
                    for (int k = 0; k < 5; ++k) {
                        u0b += wL[k][0]*wR[k][b];
                        u1b += wL[k][1]*wR[k][b];
                    }
                    r[b] -= u0b*iv0 + u1b*iv1;
                }
            }
        }
        if (t == 0) {
            // eliminate hard constraints x0=iv0, x1=iv1 (exactly as round 1)
            const double iv0 = (double)ivP[0];
            const double iv1 = (double)ivP[1];
            r[2] -= D[2*3+0]*iv0 + D[2*3+1]*iv1;
            r[0] = iv0; r[1] = iv1;
            #pragma unroll
            for (int a = 0; a < 3; ++a) { D[0*3+a]=0.0; D[1*3+a]=0.0; D[a*3+0]=0.0; D[a*3+1]=0.0; }
            D[0] = 1.0; D[4] = 1.0;
            #pragma unroll
            for (int b = 0; b < 3; ++b) { U[0*3+b] = 0.0; U[1*3+b] = 0.0; }
        }
    }

    // ---------------- parallel cyclic reduction: 7 stages --------------------
    #pragma unroll 1
    for (int d = 1; d < NSTEP_; d <<= 1) {
        double Dinv[9];
        sym_inv3(D, Dinv);
        double* row = &sh[t * STRIDE];
        #pragma unroll
        for (int i = 0; i < 9; ++i) row[i]      = Dinv[i];
        #pragma unroll
        for (int i = 0; i < 9; ++i) row[9 + i]  = U[i];
        #pragma unroll
        for (int i = 0; i < 3; ++i) row[18 + i] = r[i];
        __syncthreads();

        double nD[9], nU[9], nr[3];
        #pragma unroll
        for (int i = 0; i < 9; ++i) { nD[i] = D[i]; nU[i] = 0.0; }
        #pragma unroll
        for (int i = 0; i < 3; ++i) nr[i] = r[i];

        if (t + d < NSTEP_) {
            const double* rp_ = &sh[(t + d) * STRIDE];
            double Tp[9];
            #pragma unroll
            for (int a = 0; a < 3; ++a)
                #pragma unroll
                for (int l = 0; l < 3; ++l) {
                    double s = 0.0;
                    #pragma unroll
                    for (int k = 0; k < 3; ++k) s += U[a*3+k] * rp_[k*3+l];  // U * Dinv_p
                    Tp[a*3+l] = s;
                }
            #pragma unroll
            for (int a = 0; a < 3; ++a) {
                #pragma unroll
                for (int b = 0; b < 3; ++b) {
                    double su = 0.0, sd = 0.0;
                    #pragma unroll
                    for (int l = 0; l < 3; ++l) {
                        su += Tp[a*3+l] * rp_[9 + l*3+b];   // Tp * U_p
                        sd += Tp[a*3+l] * U[b*3+l];         // Tp * U^T
                    }
                    nU[a*3+b] = -su;
                    nD[a*3+b] -= sd;
                }
                double sr = 0.0;
                #pragma unroll
                for (int l = 0; l < 3; ++l) sr += Tp[a*3+l] * rp_[18 + l];
                nr[a] -= sr;
            }
        }
        if (t - d >= 0) {
            const double* rm_ = &sh[(t - d) * STRIDE];
            double Tm[9];
            #pragma unroll
            for (int a = 0; a < 3; ++a)
                #pragma unroll
                for (int l = 0; l < 3; ++l) {
                    double s = 0.0;
                    #pragma unroll
                    for (int k = 0; k < 3; ++k) s += rm_[9 + k*3+a] * rm_[k*3+l]; // U_m^T * Dinv_m
                    Tm[a*3+l] = s;
                }
            #pragma unroll
            for (int a = 0; a < 3; ++a) {
                #pragma unroll
                for (int b = 0; b < 3; ++b) {
                    double sd = 0.0;
                    #pragma unroll
                    for (int l = 0; l < 3; ++l) sd += Tm[a*3+l] * rm_[9 + l*3+b]; // Tm * U_m
                    nD[a*3+b] -= sd;
                }
                double sr = 0.0;
                #pragma unroll
                for (int l = 0; l < 3; ++l) sr += Tm[a*3+l] * rm_[18 + l];
                nr[a] -= sr;
            }
        }
        __syncthreads();   // all reads done before next publish
        #pragma unroll
        for (int i = 0; i < 9; ++i) { D[i] = nD[i]; U[i] = nU[i]; }
        #pragma unroll
        for (int i = 0; i < 3; ++i) r[i] = nr[i];
    }

    // ---------------- decoupled solve + outputs ------------------------------
    double Dinv[9];
    sym_inv3(D, Dinv);
    const double x0 = Dinv[0]*r[0] + Dinv[1]*r[1] + Dinv[2]*r[2];
    const double x1 = Dinv[3]*r[0] + Dinv[4]*r[1] + Dinv[5]*r[2];
    const double x2 = Dinv[6]*r[0] + Dinv[7]*r[1] + Dinv[8]*r[2];

    float* u0 = out;
    float* u1 = out + 32768;
    float* u2 = out + 65536;
    u0[sys*NSTEP_ + t] = (float)x0;
    u1[sys*NSTEP_ + t] = (float)x1;
    u2[sys*NSTEP_ + t] = (float)x2;

    // output 3: scalar zero; output 4: steps pass-through
    if (t < NSTEP_-1) out[98305 + sys*(NSTEP_-1) + t] = hP[t];
    if (sys == 0 && t == 0) out[98304] = 0.0f;
}

extern "C" void kernel_launch(void* const* d_in, const int* in_sizes, int n_in,
                              void* d_out, int out_size, void* d_ws, size_t ws_size,
                              hipStream_t stream) {
    const float* coeffs = (const float*)d_in[0];
    const float* rhs    = (const float*)d_in[1];
    const float* ivr    = (const float*)d_in[2];
    const float* steps  = (const float*)d_in[3];
    float* out = (float*)d_out;
    (void)in_sizes; (void)n_in; (void)out_size; (void)d_ws; (void)ws_size;
    hipLaunchKernelGGL(ode_pcr_solve, dim3(NSYS_), dim3(NSTEP_), 0, stream,
                       coeffs, rhs, ivr, steps, out);
}

// Round 3
// 12.052 us; speedup vs baseline: 12.5751x; 1.0477x over previous
//
#include <hip/hip_runtime.h>

#define NSYS_ 256

// Symmetric 3x3 inverse via adjugate; reads lower triangle only.
__device__ __forceinline__ void sym_inv3(const double D[9], double Dinv[9]) {
    const double a = D[0], b = D[3], c = D[4], d = D[6], e = D[7], f = D[8];
    const double A00 = c*f - e*e;
    const double A01 = d*e - b*f;
    const double A02 = b*e - c*d;
    const double A11 = a*f - d*d;
    const double A12 = b*d - a*e;
    const double A22 = a*c - b*b;
    const double det  = a*A00 + b*A01 + d*A02;
    const double idet = 1.0 / det;
    Dinv[0] = A00*idet; Dinv[1] = A01*idet; Dinv[2] = A02*idet;
    Dinv[3] = A01*idet; Dinv[4] = A11*idet; Dinv[5] = A12*idet;
    Dinv[6] = A02*idet; Dinv[7] = A12*idet; Dinv[8] = A22*idet;
}

// Interface rows for step h (verified in rounds 1-2).
__device__ __forceinline__ void iface_rows(double h, double wL[5][3], double wR[5][3]) {
    const double ih = 1.0 / h;
    const double s1 = ih * ih;    // h^-2
    const double s0 = s1 * ih;    // h^-3
    const double hh = 0.5 * ih;   // 0.5*h^-1
    wL[0][0]= s0; wL[0][1]= s1; wL[0][2]= hh;  wR[0][0]=-s0; wR[0][1]=0.0; wR[0][2]=0.0;
    wL[1][0]=-s0; wL[1][1]=0.0; wL[1][2]=0.0;  wR[1][0]= s0; wR[1][1]=-s1; wR[1][2]= hh;
    wL[2][0]=0.0; wL[2][1]= s1; wL[2][2]= ih;  wR[2][0]=0.0; wR[2][1]=-s1; wR[2][2]=0.0;
    wL[3][0]=0.0; wL[3][1]=-s1; wL[3][2]=0.0;  wR[3][0]=0.0; wR[3][1]= s1; wR[3][2]=-ih;
    wL[4][0]=0.0; wL[4][1]=0.0; wL[4][2]=-ih;  wR[4][0]=0.0; wR[4][1]=0.0; wR[4][2]= ih;
}

// One wave (64 lanes) per system. Lane l owns block-rows 2l (even) and 2l+1
// (odd). Step 1: eliminate all odd rows locally (one cyclic-reduction level,
// one 9-double neighbor exchange). Step 2: 6-stage PCR over the 64 even rows,
// all exchanges intra-wave via conflict-free SoA LDS. Step 3: back-substitute
// odd rows. All f64.
__global__ __launch_bounds__(64)
void ode_pcr_1wave(const float* __restrict__ coeffs,
                   const float* __restrict__ rhs,
                   const float* __restrict__ ivr,
                   const float* __restrict__ steps,
                   float* __restrict__ out)
{
    const int sys = blockIdx.x;
    const int l   = threadIdx.x;           // 0..63
    const int m0  = 2*l, m1 = 2*l+1;

    const float* cP  = coeffs + (size_t)sys * 384;
    const float* rP  = rhs    + (size_t)sys * 128;
    const float* ivP = ivr    + (size_t)sys * 2;
    const float* hP  = steps  + (size_t)sys * 127;

    __shared__ double ex[2][18][64];

    const float hf0 = hP[m0];                       // h_{2l}, always valid (2l<=126)
    const float hf1 = (l < 63) ? hP[m1] : 0.0f;     // h_{2l+1}

    // ---------------- assembly: rows m0, m1 ---------------------------------
    double D0[9], U0[9], r0[3], D1[9], U1[9], r1[3];
    {
        const double c0[3] = {(double)cP[m0*3+0], (double)cP[m0*3+1], (double)cP[m0*3+2]};
        const double c1[3] = {(double)cP[m1*3+0], (double)cP[m1*3+1], (double)cP[m1*3+2]};
        const double rv0 = (double)rP[m0], rv1 = (double)rP[m1];
        #pragma unroll
        for (int a=0;a<3;++a){
          #pragma unroll
          for (int b=0;b<3;++b){ D0[a*3+b]=c0[a]*c0[b]; D1[a*3+b]=c1[a]*c1[b];
                                 U0[a*3+b]=0.0;        U1[a*3+b]=0.0; }
          r0[a]=c0[a]*rv0; r1[a]=c1[a]*rv1;
        }
    }
    { // interface at h_{m0}: D0 (left side), U0, D1 (right side)
        double wL[5][3], wR[5][3];
        iface_rows((double)hf0, wL, wR);
        #pragma unroll
        for (int k=0;k<5;++k)
          #pragma unroll
          for (int a=0;a<3;++a)
            #pragma unroll
            for (int b=0;b<3;++b){
              D0[a*3+b] += wL[k][a]*wL[k][b];
              U0[a*3+b] += wL[k][a]*wR[k][b];
              D1[a*3+b] += wR[k][a]*wR[k][b];
            }
    }
    if (l >= 1) { // interface at h_{m0-1}: D0 (right side)
        double wL[5][3], wR[5][3];
        iface_rows((double)hP[m0-1], wL, wR);
        #pragma unroll
        for (int k=0;k<5;++k)
          #pragma unroll
          for (int a=0;a<3;++a)
            #pragma unroll
            for (int b=0;b<3;++b)
              D0[a*3+b] += wR[k][a]*wR[k][b];
    }
    if (l < 63) { // interface at h_{m1}: D1 (left side), U1
        double wL[5][3], wR[5][3];
        iface_rows((double)hf1, wL, wR);
        #pragma unroll
        for (int k=0;k<5;++k)
          #pragma unroll
          for (int a=0;a<3;++a)
            #pragma unroll
            for (int b=0;b<3;++b){
              D1[a*3+b] += wL[k][a]*wL[k][b];
              U1[a*3+b] += wL[k][a]*wR[k][b];
            }
    }
    if (l == 0) { // hard-constraint elimination x0[0]=iv0, x0[1]=iv1 (rows 0,1 of global G)
        const double iv0 = (double)ivP[0], iv1 = (double)ivP[1];
        #pragma unroll
        for (int b=0;b<3;++b) r1[b] -= U0[0*3+b]*iv0 + U0[1*3+b]*iv1;  // uses ORIGINAL U0
        #pragma unroll
        for (int b=0;b<3;++b){ U0[0*3+b]=0.0; U0[1*3+b]=0.0; }
        r0[2] -= D0[6]*iv0 + D0[7]*iv1;
        r0[0] = iv0; r0[1] = iv1;
        D0[1]=D0[2]=D0[3]=D0[5]=D0[6]=D0[7]=0.0;
        D0[0]=1.0; D0[4]=1.0;
    }

    // ---------------- eliminate odd row m1 (local CR level) ------------------
    double TA[9], TB[9], z1[3];
    {
        double Dinv1[9]; sym_inv3(D1, Dinv1);
        #pragma unroll
        for (int a=0;a<3;++a)
          #pragma unroll
          for (int k=0;k<3;++k){
            double s=0.0, s2=0.0;
            #pragma unroll
            for (int j=0;j<3;++j){ s  += U0[a*3+j]*Dinv1[j*3+k];     // TA = U0*Dinv1
                                   s2 += Dinv1[a*3+j]*U1[j*3+k]; }   // TB = Dinv1*U1
            TA[a*3+k]=s; TB[a*3+k]=s2;
          }
        #pragma unroll
        for (int j=0;j<3;++j)
          z1[j] = Dinv1[j*3+0]*r1[0] + Dinv1[j*3+1]*r1[1] + Dinv1[j*3+2]*r1[2];
    }
    double D[9], U[9], r[3];
    #pragma unroll
    for (int a=0;a<3;++a){
      #pragma unroll
      for (int b=0;b<3;++b){
        double sd=0.0, su=0.0;
        #pragma unroll
        for (int j=0;j<3;++j){ sd += TA[a*3+j]*U0[b*3+j];    // TA*U0^T
                               su += TA[a*3+j]*U1[j*3+b]; }  // TA*U1
        D[a*3+b] = D0[a*3+b] - sd;
        U[a*3+b] = -su;
      }
      r[a] = r0[a] - (TA[a*3+0]*r1[0] + TA[a*3+1]*r1[1] + TA[a*3+2]*r1[2]);
    }
    { // export to lane l+1: Cn = U1^T*Dinv1*U1 (sym6), cn = U1^T*z1
        double Cn[9], cn[3];
        #pragma unroll
        for (int a=0;a<3;++a){
          #pragma unroll
          for (int b=0;b<3;++b){
            double s=0.0;
            #pragma unroll
            for (int j=0;j<3;++j) s += U1[j*3+a]*TB[j*3+b];
            Cn[a*3+b]=s;
          }
          cn[a] = U1[0*3+a]*z1[0] + U1[1*3+a]*z1[1] + U1[2*3+a]*z1[2];
        }
        ex[0][0][l]=Cn[0]; ex[0][1][l]=Cn[1]; ex[0][2][l]=Cn[2];
        ex[0][3][l]=Cn[4]; ex[0][4][l]=Cn[5]; ex[0][5][l]=Cn[8];
        ex[0][6][l]=cn[0]; ex[0][7][l]=cn[1]; ex[0][8][l]=cn[2];
    }
    __syncthreads();
    if (l >= 1) {
        const int p = l-1;
        const double C0=ex[0][0][p], C1=ex[0][1][p], C2=ex[0][2][p],
                     C3=ex[0][3][p], C4=ex[0][4][p], C5=ex[0][5][p];
        D[0]-=C0; D[1]-=C1; D[2]-=C2;
        D[3]-=C1; D[4]-=C3; D[5]-=C4;
        D[6]-=C2; D[7]-=C4; D[8]-=C5;
        r[0]-=ex[0][6][p]; r[1]-=ex[0][7][p]; r[2]-=ex[0][8][p];
    }
    __syncthreads();

    // ---------------- PCR over 64 even rows: 6 stages ------------------------
    int s = 0;
    for (int d = 1; d < 64; d <<= 1, ++s) {
        double Dinv[9]; sym_inv3(D, Dinv);
        double (*buf)[64] = ex[s & 1];
        buf[0][l]=Dinv[0]; buf[1][l]=Dinv[1]; buf[2][l]=Dinv[2];
        buf[3][l]=Dinv[4]; buf[4][l]=Dinv[5]; buf[5][l]=Dinv[8];
        #pragma unroll
        for (int i=0;i<9;++i) buf[6+i][l]=U[i];
        buf[15][l]=r[0]; buf[16][l]=r[1]; buf[17][l]=r[2];
        __syncthreads();

        double nD[9], nU[9], nr[3];
        #pragma unroll
        for (int i=0;i<9;++i){ nD[i]=D[i]; nU[i]=0.0; }
        nr[0]=r[0]; nr[1]=r[1]; nr[2]=r[2];

        if (l + d < 64) {
            const int p = l + d;
            double Dp[9], Up[9], rp[3];
            Dp[0]=buf[0][p]; Dp[1]=buf[1][p]; Dp[2]=buf[2][p];
            Dp[3]=Dp[1];     Dp[4]=buf[3][p]; Dp[5]=buf[4][p];
            Dp[6]=Dp[2];     Dp[7]=Dp[5];     Dp[8]=buf[5][p];
            #pragma unroll
            for (int i=0;i<9;++i) Up[i]=buf[6+i][p];
            rp[0]=buf[15][p]; rp[1]=buf[16][p]; rp[2]=buf[17][p];
            double Tp[9];
            #pragma unroll
            for (int a=0;a<3;++a)
              #pragma unroll
              for (int k=0;k<3;++k)
                Tp[a*3+k] = U[a*3+0]*Dp[0*3+k] + U[a*3+1]*Dp[1*3+k] + U[a*3+2]*Dp[2*3+k];
            #pragma unroll
            for (int a=0;a<3;++a){
              #pragma unroll
              for (int b=0;b<3;++b){
                double su=0.0, sd=0.0;
                #pragma unroll
                for (int j=0;j<3;++j){ su += Tp[a*3+j]*Up[j*3+b]; sd += Tp[a*3+j]*U[b*3+j]; }
                nU[a*3+b] = -su;
                nD[a*3+b] -= sd;
              }
              nr[a] -= Tp[a*3+0]*rp[0] + Tp[a*3+1]*rp[1] + Tp[a*3+2]*rp[2];
            }
        }
        if (l - d >= 0) {
            const int p = l - d;
            double Dm[9], Um[9], rm[3];
            Dm[0]=buf[0][p]; Dm[1]=buf[1][p]; Dm[2]=buf[2][p];
            Dm[3]=Dm[1];     Dm[4]=buf[3][p]; Dm[5]=buf[4][p];
            Dm[6]=Dm[2];     Dm[7]=Dm[5];     Dm[8]=buf[5][p];
            #pragma unroll
            for (int i=0;i<9;++i) Um[i]=buf[6+i][p];
            rm[0]=buf[15][p]; rm[1]=buf[16][p]; rm[2]=buf[17][p];
            double Tm[9];
            #pragma unroll
            for (int a=0;a<3;++a)
              #pragma unroll
              for (int k=0;k<3;++k)
                Tm[a*3+k] = Um[0*3+a]*Dm[0*3+k] + Um[1*3+a]*Dm[1*3+k] + Um[2*3+a]*Dm[2*3+k];
            #pragma unroll
            for (int a=0;a<3;++a){
              #pragma unroll
              for (int b=0;b<3;++b){
                double sd=0.0;
                #pragma unroll
                for (int j=0;j<3;++j) sd += Tm[a*3+j]*Um[j*3+b];
                nD[a*3+b] -= sd;
              }
              nr[a] -= Tm[a*3+0]*rm[0] + Tm[a*3+1]*rm[1] + Tm[a*3+2]*rm[2];
            }
        }
        #pragma unroll
        for (int i=0;i<9;++i){ D[i]=nD[i]; U[i]=nU[i]; }
        r[0]=nr[0]; r[1]=nr[1]; r[2]=nr[2];
    }

    // ---------------- decoupled even solve + odd back-substitution ----------
    double Dinv[9]; sym_inv3(D, Dinv);
    const double xe0 = Dinv[0]*r[0] + Dinv[1]*r[1] + Dinv[2]*r[2];
    const double xe1 = Dinv[3]*r[0] + Dinv[4]*r[1] + Dinv[5]*r[2];
    const double xe2 = Dinv[6]*r[0] + Dinv[7]*r[1] + Dinv[8]*r[2];
    ex[0][0][l]=xe0; ex[0][1][l]=xe1; ex[0][2][l]=xe2;   // last stage used buf 1
    __syncthreads();
    double xN[3] = {0.0, 0.0, 0.0};
    if (l < 63) { xN[0]=ex[0][0][l+1]; xN[1]=ex[0][1][l+1]; xN[2]=ex[0][2][l+1]; }
    double xo[3];
    #pragma unroll
    for (int j=0;j<3;++j)
        xo[j] = z1[j] - (TA[0*3+j]*xe0 + TA[1*3+j]*xe1 + TA[2*3+j]*xe2)
                      - (TB[j*3+0]*xN[0] + TB[j*3+1]*xN[1] + TB[j*3+2]*xN[2]);

    // ---------------- outputs ------------------------------------------------
    float2* o0 = (float2*)(out)         + (size_t)sys*64;
    float2* o1 = (float2*)(out + 32768) + (size_t)sys*64;
    float2* o2 = (float2*)(out + 65536) + (size_t)sys*64;
    o0[l] = make_float2((float)xe0, (float)xo[0]);
    o1[l] = make_float2((float)xe1, (float)xo[1]);
    o2[l] = make_float2((float)xe2, (float)xo[2]);
    float* outH = out + 98305 + (size_t)sys*127;
    outH[m0] = hf0;
    if (l < 63) outH[m1] = hf1;
    if (sys == 0 && l == 0) out[98304] = 0.0f;
}

extern "C" void kernel_launch(void* const* d_in, const int* in_sizes, int n_in,
                              void* d_out, int out_size, void* d_ws, size_t ws_size,
                              hipStream_t stream) {
    const float* coeffs = (const float*)d_in[0];
    const float* rhs    = (const float*)d_in[1];
    const float* ivr    = (const float*)d_in[2];
    const float* steps  = (const float*)d_in[3];
    float* out = (float*)d_out;
    (void)in_sizes; (void)n_in; (void)out_size; (void)d_ws; (void)ws_size;
    hipLaunchKernelGGL(ode_pcr_1wave, dim3(NSYS_), dim3(64), 0, stream,
                       coeffs, rhs, ivr, steps, out);
}